// Round 6
// baseline (218.618 us; speedup 1.0000x reference)
//
#include <hip/hip_runtime.h>

#define B_ 8
#define A_ 98304
#define C_ 80
#define M_ 32
#define BLK 256
#define ITERS 20                 // (BLK anchors * C_/4) / BLK threads
#define NWAVE (BLK / 64)
#define TILES_PER_IMG (A_ / BLK) // 384
#define NTILES (B_ * TILES_PER_IMG) // 3072
#define GRID 2048                // 8 blocks/CU exactly

// phase-2 term: u = p^2 * log2(1-p); negative-anchor loss = 0.75*p^2*(-ln(1-p)) = u * NEGC
#define NEGC (-0.75f * 0.69314718055994531f)

// negative-form core (IDENTICAL in phase-1 correction and phase-2 sweep).
// Lower clamp dropped: for p<1e-4 the term is < 1.5e-12 (validated R4/R5, absmax 0).
__device__ __forceinline__ float neg_u(float praw) {
    const float p = fminf(praw, 1.0f - 1e-4f);
    return p * p * __log2f(1.0f - p);
}

__device__ __forceinline__ float smooth_l1(float t, float r) {
    float d = fabsf(t - r);
    return (d <= (1.0f / 9.0f)) ? (0.5f * 9.0f * d * d) : (d - 0.5f / 9.0f);
}

__global__ __launch_bounds__(BLK, 8) void focal_main(
    const float* __restrict__ cls,      // [B,A,C]
    const float* __restrict__ regr,     // [B,A,4]
    const float* __restrict__ anchors,  // [A,4]
    const float* __restrict__ ann,      // [B,M,5]
    const float* __restrict__ neg_thr_p,
    const float* __restrict__ pos_thr_p,
    float* __restrict__ acc,            // [B,3] : cls_sum, reg_sum, num_pos
    int* __restrict__ tile_counter)     // work-stealing queue head (zeroed per launch)
{
    __shared__ float s_x0[M_], s_y0[M_], s_x1[M_], s_y1[M_], s_ab[M_], s_cls[M_];
    __shared__ float s_w[BLK];
    __shared__ float s_red[NWAVE * 3];
    __shared__ int   s_tile;

    const int tid = threadIdx.x;
    const float neg_thr = neg_thr_p[0];
    const float pos_thr = pos_thr_p[0];

    for (;;) {
        // claim next tile (uniform across block; barrier also protects LDS reuse)
        if (tid == 0) s_tile = atomicAdd(tile_counter, 1);
        __syncthreads();
        const int t = s_tile;
        if (t >= NTILES) break;

        const int b  = t / TILES_PER_IMG;
        const int a0 = (t % TILES_PER_IMG) * BLK;

        if (tid < M_) {
            const float* am = ann + ((size_t)b * M_ + tid) * 5;
            const float x0 = am[0], y0 = am[1], x1 = am[2], y1 = am[3], cl = am[4];
            s_x0[tid] = x0; s_y0[tid] = y0; s_x1[tid] = x1; s_y1[tid] = y1;
            s_ab[tid] = (x1 - x0) * (y1 - y0);
            s_cls[tid] = cl;
        }
        __syncthreads();

        // ---- phase 1: IoU argmax via cross-multiplication (no divisions) ----
        const int a = a0 + tid;
        const float4 an = reinterpret_cast<const float4*>(anchors)[a];
        const float aw = an.z - an.x;
        const float ah = an.w - an.y;
        const float areaA = aw * ah;

        float ib = -1.0f, ub = 1.0f;   // best inter / best union (iou = ib/ub)
        int   arg = 0;
#pragma unroll
        for (int m = 0; m < M_; ++m) {
            const float iw = fmaxf(fminf(an.z, s_x1[m]) - fmaxf(an.x, s_x0[m]), 0.0f);
            const float ih = fmaxf(fminf(an.w, s_y1[m]) - fmaxf(an.y, s_y0[m]), 0.0f);
            float inter = iw * ih;
            const float ua = fmaxf(areaA + s_ab[m] - inter, 1e-8f);
            if (s_cls[m] == -1.0f) inter = -1.0f;      // invalid annotation -> iou -1
            if (inter * ub > ib * ua) { ib = inter; ub = ua; arg = m; }
        }
        const bool pos = (ib >= pos_thr * ub);
        const bool neg = (ib <  neg_thr * ub);

        float reg_partial = 0.0f;
        float pos_count   = 0.0f;
        float cls_corr    = 0.0f;

        if (pos) {
            pos_count = 1.0f;
            const float gx0 = s_x0[arg], gy0 = s_y0[arg];
            const float gx1 = s_x1[arg], gy1 = s_y1[arg];
            const int   kcls = (int)s_cls[arg];

            float gw = gx1 - gx0;
            float gh = gy1 - gy0;
            const float gcx = gx0 + 0.5f * gw;
            const float gcy = gy0 + 0.5f * gh;
            gw = fmaxf(gw, 1.0f);
            gh = fmaxf(gh, 1.0f);
            const float acx = an.x + 0.5f * aw;
            const float acy = an.y + 0.5f * ah;
            const float t0 = ((gcx - acx) / aw) * 10.0f;
            const float t1 = ((gcy - acy) / ah) * 10.0f;
            const float t2 = logf(gw / aw) * 5.0f;
            const float t3 = logf(gh / ah) * 5.0f;
            const float4 r = reinterpret_cast<const float4*>(regr)[(size_t)b * A_ + a];
            reg_partial = smooth_l1(t0, r.x) + smooth_l1(t1, r.y) +
                          smooth_l1(t2, r.z) + smooth_l1(t3, r.w);

            // replace phase-2's neg-form on the assigned class with the pos-form
            const float praw = cls[((size_t)b * A_ + a) * C_ + kcls];
            const float p  = fminf(fmaxf(praw, 1e-4f), 1.0f - 1e-4f);
            const float om = 1.0f - p;
            const float negv = neg_u(praw) * NEGC;
            const float posv = 0.25f * om * om * (-__logf(p));
            cls_corr = posv - negv;
        }
        s_w[tid] = (pos || neg) ? NEGC : 0.0f;         // ignored anchors weight 0
        __syncthreads();

        // ---- phase 2: coalesced float4 sweep over the 256x80 tile ----
        const float4* tile4 = reinterpret_cast<const float4*>(
            cls + ((size_t)b * A_ + a0) * C_);
        float s0 = 0.0f, s1 = 0.0f;
#pragma unroll 5
        for (int it = 0; it < ITERS; ++it) {
            const int vid = it * BLK + tid;
            const float4 v = tile4[vid];
            const float cw = s_w[(unsigned)vid / 20u]; // 20 float4 per anchor row
            s0 = fmaf(neg_u(v.x) + neg_u(v.y), cw, s0);
            s1 = fmaf(neg_u(v.z) + neg_u(v.w), cw, s1);
        }
        float cls_partial = cls_corr + s0 + s1;

        // ---- block reduction: 3 values ----
#pragma unroll
        for (int off = 32; off > 0; off >>= 1) {
            cls_partial += __shfl_down(cls_partial, off);
            reg_partial += __shfl_down(reg_partial, off);
            pos_count   += __shfl_down(pos_count,   off);
        }
        const int wave = tid >> 6;
        if ((tid & 63) == 0) {
            s_red[wave * 3 + 0] = cls_partial;
            s_red[wave * 3 + 1] = reg_partial;
            s_red[wave * 3 + 2] = pos_count;
        }
        __syncthreads();
        if (tid == 0) {
            float c = 0.0f, r = 0.0f, n = 0.0f;
#pragma unroll
            for (int wv = 0; wv < NWAVE; ++wv) {
                c += s_red[wv * 3 + 0];
                r += s_red[wv * 3 + 1];
                n += s_red[wv * 3 + 2];
            }
            atomicAdd(&acc[b * 3 + 0], c);
            atomicAdd(&acc[b * 3 + 1], r);
            atomicAdd(&acc[b * 3 + 2], n);
        }
        __syncthreads();   // protect s_red/s_ann before next tile overwrites
    }
}

__global__ void focal_finalize(const float* __restrict__ acc, float* __restrict__ out) {
    const int t = threadIdx.x;
    float cls_l = 0.0f, reg_l = 0.0f;
    if (t < B_) {
        const float np = acc[t * 3 + 2];
        cls_l = acc[t * 3 + 0] / fmaxf(np, 1.0f);
        reg_l = acc[t * 3 + 1] / fmaxf(np * 4.0f, 1.0f);
    }
#pragma unroll
    for (int off = 32; off > 0; off >>= 1) {
        cls_l += __shfl_down(cls_l, off);
        reg_l += __shfl_down(reg_l, off);
    }
    if (t == 0) {
        out[0] = cls_l / (float)B_;
        out[1] = reg_l / (float)B_;
    }
}

extern "C" void kernel_launch(void* const* d_in, const int* in_sizes, int n_in,
                              void* d_out, int out_size, void* d_ws, size_t ws_size,
                              hipStream_t stream) {
    const float* cls     = (const float*)d_in[0];
    const float* regr    = (const float*)d_in[1];
    const float* anchors = (const float*)d_in[2];
    const float* ann     = (const float*)d_in[3];
    const float* negt    = (const float*)d_in[4];
    const float* post    = (const float*)d_in[5];

    float* acc = (float*)d_ws;                       // [B,3] floats
    int*   cnt = (int*)((char*)d_ws + 256);          // work-queue head

    hipMemsetAsync(d_ws, 0, 512, stream);            // zero acc + counter
    focal_main<<<GRID, BLK, 0, stream>>>(cls, regr, anchors, ann,
                                         negt, post, acc, cnt);
    focal_finalize<<<1, 64, 0, stream>>>(acc, (float*)d_out);
}

// Round 7
// 114.955 us; speedup vs baseline: 1.9018x; 1.9018x over previous
//
#include <hip/hip_runtime.h>

#define B_ 8
#define A_ 98304
#define C_ 80
#define M_ 32
#define BLK 256
#define ITERS 20                    // (BLK anchors * C_/4) / BLK threads
#define NWAVE (BLK / 64)
#define TILES_PER_IMG (A_ / BLK)    // 384
#define NTILES (B_ * TILES_PER_IMG) // 3072
#define GRID 1536                   // 6 blocks/CU, exactly 2 tiles per block

// phase-2 term: u = p^2 * log2(1-p); negative-anchor loss = 0.75*p^2*(-ln(1-p)) = u * NEGC
#define NEGC (-0.75f * 0.69314718055994531f)

// negative-form core (IDENTICAL in phase-1 correction and phase-2 sweep).
// Lower clamp dropped: for p<1e-4 the term is < 1.5e-12 (validated R4/R5, absmax 0).
__device__ __forceinline__ float neg_u(float praw) {
    const float p = fminf(praw, 1.0f - 1e-4f);
    return p * p * __log2f(1.0f - p);
}

__device__ __forceinline__ float smooth_l1(float t, float r) {
    float d = fabsf(t - r);
    return (d <= (1.0f / 9.0f)) ? (0.5f * 9.0f * d * d) : (d - 0.5f / 9.0f);
}

__global__ __launch_bounds__(BLK) void focal_main(
    const float* __restrict__ cls,      // [B,A,C]
    const float* __restrict__ regr,     // [B,A,4]
    const float* __restrict__ anchors,  // [A,4]
    const float* __restrict__ ann,      // [B,M,5]
    const float* __restrict__ neg_thr_p,
    const float* __restrict__ pos_thr_p,
    float* __restrict__ acc)            // [B,3] : cls_sum, reg_sum, num_pos
{
    __shared__ float s_x0[M_], s_y0[M_], s_x1[M_], s_y1[M_], s_ab[M_], s_cls[M_];
    __shared__ float s_w[BLK];
    __shared__ float s_red[NWAVE * 3];

    const int tid = threadIdx.x;
    const float neg_thr = neg_thr_p[0];
    const float pos_thr = pos_thr_p[0];

    // exactly 2 tiles per block: t and t + GRID  (uniform work, no tail)
    for (int t = blockIdx.x; t < NTILES; t += GRID) {
        const int b  = t / TILES_PER_IMG;
        const int a0 = (t % TILES_PER_IMG) * BLK;

        if (tid < M_) {
            const float* am = ann + ((size_t)b * M_ + tid) * 5;
            const float x0 = am[0], y0 = am[1], x1 = am[2], y1 = am[3], cl = am[4];
            s_x0[tid] = x0; s_y0[tid] = y0; s_x1[tid] = x1; s_y1[tid] = y1;
            s_ab[tid] = (x1 - x0) * (y1 - y0);
            s_cls[tid] = cl;
        }
        __syncthreads();

        // ---- phase 1: IoU argmax via cross-multiplication (no divisions) ----
        const int a = a0 + tid;
        const float4 an = reinterpret_cast<const float4*>(anchors)[a];
        const float aw = an.z - an.x;
        const float ah = an.w - an.y;
        const float areaA = aw * ah;

        float ib = -1.0f, ub = 1.0f;   // best inter / best union (iou = ib/ub)
        int   arg = 0;
#pragma unroll
        for (int m = 0; m < M_; ++m) {
            const float iw = fmaxf(fminf(an.z, s_x1[m]) - fmaxf(an.x, s_x0[m]), 0.0f);
            const float ih = fmaxf(fminf(an.w, s_y1[m]) - fmaxf(an.y, s_y0[m]), 0.0f);
            float inter = iw * ih;
            const float ua = fmaxf(areaA + s_ab[m] - inter, 1e-8f);
            if (s_cls[m] == -1.0f) inter = -1.0f;      // invalid annotation -> iou -1
            if (inter * ub > ib * ua) { ib = inter; ub = ua; arg = m; }
        }
        const bool pos = (ib >= pos_thr * ub);
        const bool neg = (ib <  neg_thr * ub);

        float reg_partial = 0.0f;
        float pos_count   = 0.0f;
        float cls_corr    = 0.0f;

        if (pos) {
            pos_count = 1.0f;
            const float gx0 = s_x0[arg], gy0 = s_y0[arg];
            const float gx1 = s_x1[arg], gy1 = s_y1[arg];
            const int   kcls = (int)s_cls[arg];

            float gw = gx1 - gx0;
            float gh = gy1 - gy0;
            const float gcx = gx0 + 0.5f * gw;
            const float gcy = gy0 + 0.5f * gh;
            gw = fmaxf(gw, 1.0f);
            gh = fmaxf(gh, 1.0f);
            const float acx = an.x + 0.5f * aw;
            const float acy = an.y + 0.5f * ah;
            const float t0 = ((gcx - acx) / aw) * 10.0f;
            const float t1 = ((gcy - acy) / ah) * 10.0f;
            const float t2 = logf(gw / aw) * 5.0f;
            const float t3 = logf(gh / ah) * 5.0f;
            const float4 r = reinterpret_cast<const float4*>(regr)[(size_t)b * A_ + a];
            reg_partial = smooth_l1(t0, r.x) + smooth_l1(t1, r.y) +
                          smooth_l1(t2, r.z) + smooth_l1(t3, r.w);

            // replace phase-2's neg-form on the assigned class with the pos-form
            const float praw = cls[((size_t)b * A_ + a) * C_ + kcls];
            const float p  = fminf(fmaxf(praw, 1e-4f), 1.0f - 1e-4f);
            const float om = 1.0f - p;
            const float negv = neg_u(praw) * NEGC;
            const float posv = 0.25f * om * om * (-__logf(p));
            cls_corr = posv - negv;
        }
        s_w[tid] = (pos || neg) ? NEGC : 0.0f;         // ignored anchors weight 0
        __syncthreads();

        // ---- phase 2: coalesced float4 sweep over the 256x80 tile ----
        const float4* tile4 = reinterpret_cast<const float4*>(
            cls + ((size_t)b * A_ + a0) * C_);
        float s0 = 0.0f, s1 = 0.0f;
#pragma unroll 5
        for (int it = 0; it < ITERS; ++it) {
            const int vid = it * BLK + tid;
            const float4 v = tile4[vid];
            const float cw = s_w[(unsigned)vid / 20u]; // 20 float4 per anchor row
            s0 = fmaf(neg_u(v.x) + neg_u(v.y), cw, s0);
            s1 = fmaf(neg_u(v.z) + neg_u(v.w), cw, s1);
        }
        float cls_partial = cls_corr + s0 + s1;

        // ---- block reduction: 3 values ----
#pragma unroll
        for (int off = 32; off > 0; off >>= 1) {
            cls_partial += __shfl_down(cls_partial, off);
            reg_partial += __shfl_down(reg_partial, off);
            pos_count   += __shfl_down(pos_count,   off);
        }
        const int wave = tid >> 6;
        if ((tid & 63) == 0) {
            s_red[wave * 3 + 0] = cls_partial;
            s_red[wave * 3 + 1] = reg_partial;
            s_red[wave * 3 + 2] = pos_count;
        }
        __syncthreads();
        if (tid == 0) {
            float c = 0.0f, r = 0.0f, n = 0.0f;
#pragma unroll
            for (int wv = 0; wv < NWAVE; ++wv) {
                c += s_red[wv * 3 + 0];
                r += s_red[wv * 3 + 1];
                n += s_red[wv * 3 + 2];
            }
            atomicAdd(&acc[b * 3 + 0], c);
            atomicAdd(&acc[b * 3 + 1], r);
            atomicAdd(&acc[b * 3 + 2], n);
        }
        __syncthreads();   // protect s_* reuse by next tile
    }
}

__global__ void focal_finalize(const float* __restrict__ acc, float* __restrict__ out) {
    const int t = threadIdx.x;
    float cls_l = 0.0f, reg_l = 0.0f;
    if (t < B_) {
        const float np = acc[t * 3 + 2];
        cls_l = acc[t * 3 + 0] / fmaxf(np, 1.0f);
        reg_l = acc[t * 3 + 1] / fmaxf(np * 4.0f, 1.0f);
    }
#pragma unroll
    for (int off = 32; off > 0; off >>= 1) {
        cls_l += __shfl_down(cls_l, off);
        reg_l += __shfl_down(reg_l, off);
    }
    if (t == 0) {
        out[0] = cls_l / (float)B_;
        out[1] = reg_l / (float)B_;
    }
}

extern "C" void kernel_launch(void* const* d_in, const int* in_sizes, int n_in,
                              void* d_out, int out_size, void* d_ws, size_t ws_size,
                              hipStream_t stream) {
    const float* cls     = (const float*)d_in[0];
    const float* regr    = (const float*)d_in[1];
    const float* anchors = (const float*)d_in[2];
    const float* ann     = (const float*)d_in[3];
    const float* negt    = (const float*)d_in[4];
    const float* post    = (const float*)d_in[5];
    float* acc = (float*)d_ws;

    hipMemsetAsync(acc, 0, B_ * 3 * sizeof(float), stream);
    focal_main<<<GRID, BLK, 0, stream>>>(cls, regr, anchors, ann,
                                         negt, post, acc);
    focal_finalize<<<1, 64, 0, stream>>>(acc, (float*)d_out);
}